// Round 2
// baseline (349.154 us; speedup 1.0000x reference)
//
#include <hip/hip_runtime.h>
#include <math.h>

// f32-rounded pi / 2pi, matching JAX's f64->f32 weak-type folding:
#define PI_F    3.14159274101257324e0f   /* 0x40490FDB */
#define TWOPI_F 6.28318548202514648e0f   /* 0x40C90FDB */
#define SENT_F  1000000.0f

// Duplicate mask for a group of N objects starting at object OFF, reading
// (pt,eta,phi) triplets from row pointer r (LDS). Bit (OFF+j) set <=> exists
// i>j in group with dR(i,j) < 0.05. Bit-exact vs numpy f32: fmod+adjust for
// jnp.mod, no FMA contraction, correctly-rounded sqrt.
template <int OFF, int N>
__device__ __forceinline__ unsigned group_dup(const float* r) {
    float e[N], p[N];
#pragma unroll
    for (int k = 0; k < N; ++k) {
        float pt = r[3 * (OFF + k) + 0];
        bool act = pt > 0.0f;
        e[k] = act ? r[3 * (OFF + k) + 1] : SENT_F;
        p[k] = act ? r[3 * (OFF + k) + 2] : SENT_F;
    }
    unsigned dup = 0;
#pragma unroll
    for (int j = 0; j < N - 1; ++j) {
        bool d = false;
#pragma unroll
        for (int i = j + 1; i < N; ++i) {
            float deta = e[i] - e[j];
            float dd   = (p[i] - p[j]) + PI_F;
            float m    = fmodf(dd, TWOPI_F);               // exact remainder (lax.rem)
            m = (m < 0.0f) ? (m + TWOPI_F) : m;            // numpy-mod sign adjust
            float dphi = m - PI_F;
            float dr2 = __fadd_rn(__fmul_rn(deta, deta), __fmul_rn(dphi, dphi));
            float dr  = __fsqrt_rn(dr2);
            d = d || (dr < 0.05f);
        }
        if (d) dup |= (1u << (OFF + j));
    }
    return dup;
}

// Block = 256 threads = 256 rows. Coalesced float4 global I/O via LDS staging:
//   load:  thread t loads float4 #(t + 256*i), i=0..11  (coalesced), keeps in
//          regs AND mirrors into LDS row-major (48 floats/row, lane stride 48
//          -> 2-way bank aliasing, free on gfx950).
//   mask:  thread t computes 15-bit dup mask for row t from LDS scalar reads.
//   store: thread t zeroes components of its registered float4s per mask[row],
//          coalesced float4 store. Object idx = float_idx/3; bit 15 (MET)
//          never set -> passthrough.
__global__ __launch_bounds__(256) void dup_removal_kernel(
    const float4* __restrict__ in, float4* __restrict__ out, int B) {
    __shared__ float rowbuf[256 * 48];       // 48 KB
    __shared__ unsigned maskbuf[256];

    const int t = threadIdx.x;
    const long long base4  = (long long)blockIdx.x * 3072;  // float4 units
    const long long total4 = (long long)B * 12;

    float4 v[12];
#pragma unroll
    for (int i = 0; i < 12; ++i) {
        long long g = base4 + t + 256 * i;
        if (g < total4) {
            v[i] = in[g];
            ((float4*)rowbuf)[t + 256 * i] = v[i];
        }
    }
    __syncthreads();

    const int row = blockIdx.x * 256 + t;
    unsigned dup = 0;
    if (row < B) {
        const float* r = rowbuf + t * 48;
        dup  = group_dup<0, 6>(r);    // jets      (objects 0..5)
        dup |= group_dup<6, 3>(r);    // electrons (objects 6..8)
        dup |= group_dup<9, 3>(r);    // muons     (objects 9..11)
        dup |= group_dup<12, 3>(r);   // photons   (objects 12..14)
    }
    maskbuf[t] = dup;
    __syncthreads();

#pragma unroll
    for (int i = 0; i < 12; ++i) {
        long long g = base4 + t + 256 * i;
        if (g < total4) {
            int local = t + 256 * i;
            int rl = local / 12;             // local row of this float4
            int f  = local - rl * 12;        // float4 index within row (0..11)
            unsigned m = maskbuf[rl];
            int k0 = 4 * f;                  // first float index in row
            float4 w = v[i];
            if ((m >> ((k0 + 0) / 3)) & 1u) w.x = 0.0f;
            if ((m >> ((k0 + 1) / 3)) & 1u) w.y = 0.0f;
            if ((m >> ((k0 + 2) / 3)) & 1u) w.z = 0.0f;
            if ((m >> ((k0 + 3) / 3)) & 1u) w.w = 0.0f;
            out[g] = w;
        }
    }
}

extern "C" void kernel_launch(void* const* d_in, const int* in_sizes, int n_in,
                              void* d_out, int out_size, void* d_ws, size_t ws_size,
                              hipStream_t stream) {
    const float4* x = (const float4*)d_in[0];
    float4* out = (float4*)d_out;
    int B = in_sizes[0] / 48;                // rows of (16,3)
    int grid = (B + 255) / 256;              // 256 rows per block
    dup_removal_kernel<<<grid, 256, 0, stream>>>(x, out, B);
}

// Round 3
// 323.488 us; speedup vs baseline: 1.0793x; 1.0793x over previous
//
#include <hip/hip_runtime.h>
#include <math.h>

// f32-rounded pi / 2pi (JAX weak-type f64->f32 folding): 0x40490FDB / 0x40C90FDB
#define PI_F        3.14159274101257324e0f
#define TWOPI_F     6.28318548202514648e0f
#define TWOPI_D     ((double)TWOPI_F)
#define INV_TWOPI_D (1.0 / (double)TWOPI_F)   // correctly-rounded f64 constant

#define ROWS_PER_BLOCK 128
#define ROW_STRIDE     49                      // 48 floats + 1 pad (odd -> conflict-free reads)

// Exact replication of: m = fmod(dd, 2pi); if (m<0) m += 2pi; dphi = m - pi;
// dr = sqrt(deta^2 + dphi^2); return dr < 0.05.
// Valid for |dd| < ~2^18 * 2pi. Bit-exact vs numpy f32:
//  - q = trunc(dd/2pi) via f64 multiply; error 2^-53 << min gap 4e-8 to integers,
//    so q is exact except when dd is an EXACT f32 multiple of 2pi, where the
//    off-by-one gives dphi = +/-pi with identical square (2pi_f32 - pi_f32 ==
//    pi_f32 exactly) -> identical decision.
//  - r = fma(-q, 2pi, dd) in f64 is exact (result spans <= 26 bits); the true
//    fmod is f32-representable, so the f32 downconvert is exact.
__device__ __forceinline__ int pair_close(float ei, float ej, float pi_, float pj) {
    float deta = __fsub_rn(ei, ej);
    float dd   = __fadd_rn(__fsub_rn(pi_, pj), PI_F);
    double ddd = (double)dd;
    double q   = trunc(ddd * INV_TWOPI_D);
    float  m   = (float)fma(-q, TWOPI_D, ddd);
    if (m < 0.0f) m = __fadd_rn(m, TWOPI_F);   // numpy floor-mod sign adjust
    float dphi = __fsub_rn(m, PI_F);
    float dr2  = __fadd_rn(__fmul_rn(deta, deta), __fmul_rn(dphi, dphi));
    return __fsqrt_rn(dr2) < 0.05f;            // correctly-rounded sqrt, as ref
}

// Dup mask for group of N objects at offset OFF, reading (pt,eta,phi) from the
// LDS row r. Pair semantics (matches sentinel construction in the reference):
//   both inactive -> dr = 0      -> dup
//   one inactive  -> dr ~ 1e6    -> not dup
//   both active   -> exact f32 dR test on raw eta/phi
template <int OFF, int N>
__device__ __forceinline__ unsigned group_dup(const float* r) {
    float e[N], p[N];
    int   a[N];
#pragma unroll
    for (int k = 0; k < N; ++k) {
        float pt = r[3 * (OFF + k) + 0];
        a[k] = pt > 0.0f;
        e[k] = r[3 * (OFF + k) + 1];
        p[k] = r[3 * (OFF + k) + 2];
    }
    unsigned dup = 0;
#pragma unroll
    for (int j = 0; j < N - 1; ++j) {
        int d = 0;
#pragma unroll
        for (int i = j + 1; i < N; ++i) {
            int close = pair_close(e[i], e[j], p[i], p[j]);
            d |= (a[i] & a[j] & close) | ((a[i] | a[j]) ^ 1);
        }
        if (d) dup |= (1u << (OFF + j));
    }
    return dup;
}

// Block = 256 threads handling 128 rows.
//   load:  thread t loads float4 #(t+256i), i=0..5 (coalesced), keeps in regs,
//          scatters 4 scalars into LDS rows of stride 49 (odd -> 2-way bank
//          aliasing on compute reads = free).
//   mask:  threads 0..127 compute the 15-bit dup mask for their row from LDS,
//          expand to a 48-bit per-float mask, store to LDS.
//   store: thread t zeroes components of its registered float4s per the row's
//          expanded mask (bit k = float k zeroed), coalesced float4 store.
__global__ __launch_bounds__(256, 6) void dup_removal_kernel(
    const float4* __restrict__ in, float4* __restrict__ out, int B) {
    __shared__ float rowbuf[ROWS_PER_BLOCK * ROW_STRIDE];   // 24.5 KB
    __shared__ unsigned long long maskbuf[ROWS_PER_BLOCK];  // 1 KB

    const int t = threadIdx.x;
    const long long base4  = (long long)blockIdx.x * (ROWS_PER_BLOCK * 12);
    const long long total4 = (long long)B * 12;

    float4 v[6];
#pragma unroll
    for (int i = 0; i < 6; ++i) {
        long long g = base4 + t + 256 * i;
        if (g < total4) {
            v[i] = in[g];
            int local = t + 256 * i;
            int rl = local / 12;
            int f  = local - rl * 12;
            float* dstp = &rowbuf[rl * ROW_STRIDE + 4 * f];
            dstp[0] = v[i].x; dstp[1] = v[i].y; dstp[2] = v[i].z; dstp[3] = v[i].w;
        }
    }
    __syncthreads();

    if (t < ROWS_PER_BLOCK) {
        int row = blockIdx.x * ROWS_PER_BLOCK + t;
        unsigned dup = 0;
        if (row < B) {
            const float* r = rowbuf + t * ROW_STRIDE;
            dup  = group_dup<0, 6>(r);    // jets      (objects 0..5)
            dup |= group_dup<6, 3>(r);    // electrons (objects 6..8)
            dup |= group_dup<9, 3>(r);    // muons     (objects 9..11)
            dup |= group_dup<12, 3>(r);   // photons   (objects 12..14)
        }
        // expand object mask -> per-float mask (bit k = zero float k, k=0..44)
        unsigned long long fm = 0ull;
#pragma unroll
        for (int o = 0; o < 15; ++o)
            fm |= (unsigned long long)((dup >> o) & 1u) * (7ull << (3 * o));
        maskbuf[t] = fm;
    }
    __syncthreads();

#pragma unroll
    for (int i = 0; i < 6; ++i) {
        long long g = base4 + t + 256 * i;
        if (g < total4) {
            int local = t + 256 * i;
            int rl = local / 12;
            int f  = local - rl * 12;
            unsigned nib = (unsigned)(maskbuf[rl] >> (4 * f)) & 0xFu;
            float4 w = v[i];
            if (nib & 1u) w.x = 0.0f;
            if (nib & 2u) w.y = 0.0f;
            if (nib & 4u) w.z = 0.0f;
            if (nib & 8u) w.w = 0.0f;
            out[g] = w;
        }
    }
}

extern "C" void kernel_launch(void* const* d_in, const int* in_sizes, int n_in,
                              void* d_out, int out_size, void* d_ws, size_t ws_size,
                              hipStream_t stream) {
    const float4* x = (const float4*)d_in[0];
    float4* out = (float4*)d_out;
    int B = in_sizes[0] / 48;                            // rows of (16,3)
    int grid = (B + ROWS_PER_BLOCK - 1) / ROWS_PER_BLOCK;
    dup_removal_kernel<<<grid, 256, 0, stream>>>(x, out, B);
}